// Round 1
// baseline (381.579 us; speedup 1.0000x reference)
//
#include <hip/hip_runtime.h>
#include <hip/hip_bf16.h>

#define Mpts 50000
#define Npts 50000
#define Hn 32
#define Cc 128
#define Kk 15
#define NCW 240   // K*CPG = 15*16

// ---- templated scratch dtype (fp32 preferred, bf16 fallback if ws small) ----
template<typename T> __device__ inline void storeT(T* p, float v);
template<> __device__ inline void storeT<float>(float* p, float v) { *p = v; }
template<> __device__ inline void storeT<__hip_bfloat16>(__hip_bfloat16* p, float v) { *p = __float2bfloat16(v); }
template<typename T> __device__ inline float loadT(const T* p);
template<> __device__ inline float loadT<float>(const float* p) { return *p; }
template<> __device__ inline float loadT<__hip_bfloat16>(const __hip_bfloat16* p) { return __bfloat162float(*p); }

// ================= K1: fused MLP (h = leaky(sf@W1+b1); cw = h@W2+b2) =========
template<typename T>
__global__ __launch_bounds__(256) void k1_mlp(
    const float* __restrict__ sfeat, const float* __restrict__ W1,
    const float* __restrict__ b1, const float* __restrict__ W2,
    const float* __restrict__ b2, T* __restrict__ cw,
    float* __restrict__ stats)
{
  __shared__ float sf[64][128];          // s_feats tile, then reused for h
  __shared__ float red[2][15][4];        // [sum/sumsq][group][wave]
  const int t = threadIdx.x;
  const int r0 = blockIdx.x * 64;
  int rows = Mpts - r0; if (rows > 64) rows = 64;

  // ---- load 64x128 tile (contiguous float4 copy, zero-pad tail) ----
  {
    const float4* src = (const float4*)(sfeat + (size_t)r0 * Cc);
    float4* dst = (float4*)(&sf[0][0]);
    const int n4 = rows * 32;
#pragma unroll
    for (int i = 0; i < 8; ++i) {
      int id = t + i * 256;
      float4 v = make_float4(0.f, 0.f, 0.f, 0.f);
      if (id < n4) v = src[id];
      dst[id] = v;
    }
  }
  __syncthreads();

  // ---- stage 1: h tile 64x128, thread = 8 rows x 4 cols ----
  const int tr = t >> 5, tc = t & 31;
  float acc[8][4];
#pragma unroll
  for (int r = 0; r < 8; ++r) { acc[r][0] = 0.f; acc[r][1] = 0.f; acc[r][2] = 0.f; acc[r][3] = 0.f; }
  for (int k = 0; k < Cc; ++k) {
    float4 w = *(const float4*)(W1 + k * Cc + tc * 4);
#pragma unroll
    for (int r = 0; r < 8; ++r) {
      float a = sf[tr * 8 + r][k];
      acc[r][0] = fmaf(a, w.x, acc[r][0]);
      acc[r][1] = fmaf(a, w.y, acc[r][1]);
      acc[r][2] = fmaf(a, w.z, acc[r][2]);
      acc[r][3] = fmaf(a, w.w, acc[r][3]);
    }
  }
  float4 bb = *(const float4*)(b1 + tc * 4);
  __syncthreads();   // all reads of sf done
#pragma unroll
  for (int r = 0; r < 8; ++r) {
    float h0 = acc[r][0] + bb.x; h0 = h0 >= 0.f ? h0 : 0.1f * h0;
    float h1 = acc[r][1] + bb.y; h1 = h1 >= 0.f ? h1 : 0.1f * h1;
    float h2 = acc[r][2] + bb.z; h2 = h2 >= 0.f ? h2 : 0.1f * h2;
    float h3 = acc[r][3] + bb.w; h3 = h3 >= 0.f ? h3 : 0.1f * h3;
    sf[tr * 8 + r][tc * 4 + 0] = h0;
    sf[tr * 8 + r][tc * 4 + 1] = h1;
    sf[tr * 8 + r][tc * 4 + 2] = h2;
    sf[tr * 8 + r][tc * 4 + 3] = h3;
  }
  __syncthreads();

  // ---- stage 2: cw tile 64x240, thread = 4 rows x 15 cols (col = tc2 + 16*j) ----
  const int tr2 = t >> 4, tc2 = t & 15;
  float a2[4][15];
#pragma unroll
  for (int r = 0; r < 4; ++r)
#pragma unroll
    for (int j = 0; j < 15; ++j) a2[r][j] = 0.f;
  for (int k = 0; k < Cc; ++k) {
    float h0 = sf[tr2 * 4 + 0][k];
    float h1 = sf[tr2 * 4 + 1][k];
    float h2 = sf[tr2 * 4 + 2][k];
    float h3 = sf[tr2 * 4 + 3][k];
    const float* wrow = W2 + k * NCW + tc2;
#pragma unroll
    for (int j = 0; j < 15; ++j) {
      float w = wrow[j * 16];
      a2[0][j] = fmaf(h0, w, a2[0][j]);
      a2[1][j] = fmaf(h1, w, a2[1][j]);
      a2[2][j] = fmaf(h2, w, a2[2][j]);
      a2[3][j] = fmaf(h3, w, a2[3][j]);
    }
  }

  float s[15], ss[15];
#pragma unroll
  for (int j = 0; j < 15; ++j) { s[j] = 0.f; ss[j] = 0.f; }
#pragma unroll
  for (int j = 0; j < 15; ++j) {
    float bias = b2[tc2 + j * 16];
#pragma unroll
    for (int r = 0; r < 4; ++r) {
      int row = tr2 * 4 + r;
      if (row < rows) {
        float v = a2[r][j] + bias;
        storeT(&cw[(size_t)(r0 + row) * NCW + tc2 + j * 16], v);
        s[j] += v; ss[j] += v * v;
      }
    }
  }
  // wave-level reduce (64 lanes), then block reduce, then global atomics
#pragma unroll
  for (int j = 0; j < 15; ++j) {
    for (int off = 32; off > 0; off >>= 1) {
      s[j]  += __shfl_xor(s[j],  off);
      ss[j] += __shfl_xor(ss[j], off);
    }
  }
  const int wid = t >> 6, lane = t & 63;
  if (lane == 0) {
#pragma unroll
    for (int j = 0; j < 15; ++j) { red[0][j][wid] = s[j]; red[1][j][wid] = ss[j]; }
  }
  __syncthreads();
  if (t < 15) {
    float S = red[0][t][0] + red[0][t][1] + red[0][t][2] + red[0][t][3];
    atomicAdd(&stats[t], S);
  } else if (t >= 16 && t < 31) {
    int j = t - 16;
    float SS = red[1][j][0] + red[1][j][1] + red[1][j][2] + red[1][j][3];
    atomicAdd(&stats[15 + j], SS);
  }
}

// ================= K2: finalize GroupNorm stats ==============================
__global__ void k2_stats(float* __restrict__ stats)
{
  int j = threadIdx.x;
  if (j < 15) {
    const float inv = 1.0f / (16.0f * (float)Mpts);   // M * CPG values per group
    float mu = stats[j] * inv;
    float var = stats[15 + j] * inv - mu * mu;
    stats[30 + j] = mu;
    stats[45 + j] = rsqrtf(var + 1e-5f);
  }
}

// ================= K3: geometry + normalize + gather-sum =====================
template<typename T>
__global__ __launch_bounds__(256) void k3_out(
    const float* __restrict__ q_pts, const float* __restrict__ s_pts,
    const float* __restrict__ sfeat, const int* __restrict__ nb,
    const float* __restrict__ kp, const float* __restrict__ gn_w,
    const float* __restrict__ gn_b, const T* __restrict__ cw,
    const float* __restrict__ stats, float* __restrict__ out)
{
  __shared__ float kpt[3][15];
  __shared__ float gnw[240], gnb[240];
  __shared__ float mus[15], rss[15];
  __shared__ float cwl[4][240];
  const int t = threadIdx.x;
  if (t < 45) kpt[t % 3][t / 3] = kp[t];
  if (t >= 64 && t < 79) { mus[t - 64] = stats[30 + (t - 64)]; rss[t - 64] = stats[45 + (t - 64)]; }
  if (t < 240) { gnw[t] = gn_w[t]; gnb[t] = gn_b[t]; }
  __syncthreads();

  const int wid = t >> 6, lane = t & 63;
  const int m = blockIdx.x * 4 + wid;    // grid = M/4 exactly

  int idx = Npts; int ksel = 0; float infl = 0.f;
  if (lane < Hn) {
    idx = nb[m * Hn + lane];
    float qx = q_pts[m * 3 + 0], qy = q_pts[m * 3 + 1], qz = q_pts[m * 3 + 2];
    float px, py, pz;
    if (idx < Npts) { px = s_pts[idx * 3 + 0]; py = s_pts[idx * 3 + 1]; pz = s_pts[idx * 3 + 2]; }
    else            { px = 1.0e6f; py = 1.0e6f; pz = 1.0e6f; }
    float nx = px - qx, ny = py - qy, nz = pz - qz;
    float best = 1e30f;
#pragma unroll
    for (int k = 0; k < Kk; ++k) {
      float dx = nx - kpt[0][k], dy = ny - kpt[1][k], dz = nz - kpt[2][k];
      float d = dx * dx + dy * dy + dz * dz;
      if (d < best) { best = d; ksel = k; }
    }
    infl = 1.f - sqrtf(best);
    infl = infl > 0.f ? infl : 0.f;
  }

  // normalized per-point weights -> LDS (240 values)
  {
    const T* cwm = cw + (size_t)m * NCW;
    for (int j = lane; j < NCW; j += 64) {
      float v = loadT(cwm + j);
      int g = j >> 4;
      cwl[wid][j] = (v - mus[g]) * rss[g] * gnw[j] + gnb[j];
    }
  }
  __syncthreads();

  // accumulate over 32 neighbors; lane owns channels {2*lane, 2*lane+1}
  float ax = 0.f, ay = 0.f;
  const int widx = lane >> 2;               // cpg index for channel 2*lane
  const float* fbase = sfeat + 2 * lane;
#pragma unroll 4
  for (int h = 0; h < Hn; ++h) {
    int   ih = __shfl(idx,  h);
    float wI = __shfl(infl, h);
    int   kh = __shfl(ksel, h);
    if (ih < Npts) {
      float2 f = *(const float2*)(fbase + (size_t)ih * Cc);
      float w = cwl[wid][kh * 16 + widx] * wI;
      ax = fmaf(f.x, w, ax);
      ay = fmaf(f.y, w, ay);
    }
  }
  float2 o; o.x = ax; o.y = ay;
  *(float2*)(out + (size_t)m * Cc + 2 * lane) = o;
}

// ================= launcher ==================================================
extern "C" void kernel_launch(void* const* d_in, const int* in_sizes, int n_in,
                              void* d_out, int out_size, void* d_ws, size_t ws_size,
                              hipStream_t stream) {
  const float* q_pts  = (const float*)d_in[0];
  const float* s_pts  = (const float*)d_in[1];
  const float* sfeat  = (const float*)d_in[2];
  const int*   nb     = (const int*)d_in[3];
  const float* kp     = (const float*)d_in[4];
  const float* W1     = (const float*)d_in[5];
  const float* b1     = (const float*)d_in[6];
  const float* W2     = (const float*)d_in[7];
  const float* b2     = (const float*)d_in[8];
  const float* gn_w   = (const float*)d_in[9];
  const float* gn_b   = (const float*)d_in[10];
  float* out   = (float*)d_out;
  float* stats = (float*)d_ws;

  hipMemsetAsync(d_ws, 0, 64 * sizeof(float), stream);   // zero sum/sumsq

  const int blocks1 = (Mpts + 63) / 64;     // 782
  const int blocks3 = Mpts / 4;             // 12500 (exact)
  const size_t need_f32 = 64 * sizeof(float) + (size_t)Mpts * NCW * sizeof(float);

  if (ws_size >= need_f32) {
    float* cw = stats + 64;
    k1_mlp<float><<<blocks1, 256, 0, stream>>>(sfeat, W1, b1, W2, b2, cw, stats);
    k2_stats<<<1, 64, 0, stream>>>(stats);
    k3_out<float><<<blocks3, 256, 0, stream>>>(q_pts, s_pts, sfeat, nb, kp, gn_w, gn_b, cw, stats, out);
  } else {
    __hip_bfloat16* cw = (__hip_bfloat16*)(stats + 64);
    k1_mlp<__hip_bfloat16><<<blocks1, 256, 0, stream>>>(sfeat, W1, b1, W2, b2, cw, stats);
    k2_stats<<<1, 64, 0, stream>>>(stats);
    k3_out<__hip_bfloat16><<<blocks3, 256, 0, stream>>>(q_pts, s_pts, sfeat, nb, kp, gn_w, gn_b, cw, stats, out);
  }
}

// Round 2
// 223.877 us; speedup vs baseline: 1.7044x; 1.7044x over previous
//
#include <hip/hip_runtime.h>
#include <hip/hip_bf16.h>

#define Mpts 50000
#define Npts 50000
#define Hn 32
#define Cc 128
#define Kk 15
#define NCW 240   // K*CPG = 15*16

typedef __attribute__((ext_vector_type(8))) short short8;
typedef __attribute__((ext_vector_type(4))) float f32x4;

__device__ inline ushort f2bf(float f) {
  __hip_bfloat16 h = __float2bfloat16(f);
  return *reinterpret_cast<ushort*>(&h);
}
__device__ inline float bf2f(ushort u) {
  return __uint_as_float(((uint)u) << 16);
}

// ================= K0: convert s_feats -> bf16; transpose W1,W2 -> bf16 [n][k]
__global__ __launch_bounds__(256) void k0_convert(
    const float* __restrict__ sfeat, const float* __restrict__ W1,
    const float* __restrict__ W2, ushort* __restrict__ sfb,
    ushort* __restrict__ W1t, ushort* __restrict__ W2t)
{
  const int t = threadIdx.x;
  const int b = blockIdx.x;
  if (b < 3125) {             // s_feats: 6,400,000 elems, 8 per thread
    const size_t base = ((size_t)b * 256 + t) * 8;
    float4 f0 = *(const float4*)(sfeat + base);
    float4 f1 = *(const float4*)(sfeat + base + 4);
    union { short8 v; ushort u[8]; } pk;
    pk.u[0] = f2bf(f0.x); pk.u[1] = f2bf(f0.y); pk.u[2] = f2bf(f0.z); pk.u[3] = f2bf(f0.w);
    pk.u[4] = f2bf(f1.x); pk.u[5] = f2bf(f1.y); pk.u[6] = f2bf(f1.z); pk.u[7] = f2bf(f1.w);
    *(short8*)(sfb + base) = pk.v;
  } else if (b == 3125) {     // W1t[n][k] = W1[k][n], 128x128
    for (int i = t; i < 128 * 128; i += 256) {
      int n = i >> 7, k = i & 127;
      W1t[i] = f2bf(W1[k * Cc + n]);
    }
  } else {                    // W2t[n][k] = W2[k][n], 240x128
    for (int i = t; i < 240 * 128; i += 256) {
      int n = i >> 7, k = i & 127;
      W2t[i] = f2bf(W2[k * NCW + n]);
    }
  }
}

// ================= K1: fused MLP via bf16 MFMA ===============================
// h = leaky(sf@W1+b1); cw = h@W2+b2 ; per-group sum/sumsq -> stats atomics
__global__ __launch_bounds__(256) void k1_mlp(
    const ushort* __restrict__ sfb, const ushort* __restrict__ W1t,
    const float* __restrict__ b1, const ushort* __restrict__ W2t,
    const float* __restrict__ b2, ushort* __restrict__ cw,
    float* __restrict__ stats)
{
  __shared__ __align__(16) ushort aT[64 * 128];   // swizzled A tile (bf16)
  __shared__ __align__(16) ushort hT[64 * 128];   // swizzled h tile (bf16)
  __shared__ float red[2][15][4];

  const int t = threadIdx.x;
  const int r0 = blockIdx.x * 64;
  const int wid = t >> 6, lane = t & 63;
  const int l16 = lane & 15, lq = lane >> 4;

  // ---- stage A tile: 64 rows x 128 cols bf16, XOR-swizzled ----
#pragma unroll
  for (int p = 0; p < 4; ++p) {
    int id = p * 256 + t;          // 16B-chunk index: row = id/16, chunk = id%16
    int r = id >> 4, c = id & 15;
    int g = r0 + r;
    short8 v = short8{0,0,0,0,0,0,0,0};
    if (g < Mpts) v = *(const short8*)(sfb + (size_t)g * Cc + c * 8);
    int byte = ((r * 256) + c * 16) ^ ((r & 7) << 4);
    *(short8*)((char*)aT + byte) = v;
  }
  __syncthreads();

  // ---- stage 1: h[16 rows per wave][128] ----
  f32x4 acc1[8];
#pragma unroll
  for (int nt = 0; nt < 8; ++nt) acc1[nt] = f32x4{0.f, 0.f, 0.f, 0.f};
  const int arow = wid * 16 + l16;
#pragma unroll
  for (int kt = 0; kt < 4; ++kt) {
    int abyte = ((arow * 256) + (kt * 32 + lq * 8) * 2) ^ ((arow & 7) << 4);
    short8 a = *(const short8*)((const char*)aT + abyte);
#pragma unroll
    for (int nt = 0; nt < 8; ++nt) {
      short8 bfr = *(const short8*)(W1t + (nt * 16 + l16) * Cc + kt * 32 + lq * 8);
      acc1[nt] = __builtin_amdgcn_mfma_f32_16x16x32_bf16(a, bfr, acc1[nt], 0, 0, 0);
    }
  }
  // bias + LeakyReLU -> hT (swizzled, wave-private rows)
#pragma unroll
  for (int nt = 0; nt < 8; ++nt) {
    int col = nt * 16 + l16;
    float bias = b1[col];
#pragma unroll
    for (int reg = 0; reg < 4; ++reg) {
      float h = acc1[nt][reg] + bias;
      h = h >= 0.f ? h : 0.1f * h;
      int row = wid * 16 + lq * 4 + reg;
      int byte = ((row * 256) + col * 2) ^ ((row & 7) << 4);
      *(ushort*)((char*)hT + byte) = f2bf(h);
    }
  }

  // ---- stage 2: cw[16 rows per wave][240] ----
  f32x4 acc2[15];
#pragma unroll
  for (int j = 0; j < 15; ++j) acc2[j] = f32x4{0.f, 0.f, 0.f, 0.f};
#pragma unroll
  for (int kt = 0; kt < 4; ++kt) {
    int abyte = ((arow * 256) + (kt * 32 + lq * 8) * 2) ^ ((arow & 7) << 4);
    short8 a = *(const short8*)((const char*)hT + abyte);
#pragma unroll
    for (int j = 0; j < 15; ++j) {
      short8 bfr = *(const short8*)(W2t + (j * 16 + l16) * Cc + kt * 32 + lq * 8);
      acc2[j] = __builtin_amdgcn_mfma_f32_16x16x32_bf16(a, bfr, acc2[j], 0, 0, 0);
    }
  }

  float s[15], ss[15];
#pragma unroll
  for (int j = 0; j < 15; ++j) { s[j] = 0.f; ss[j] = 0.f; }
#pragma unroll
  for (int j = 0; j < 15; ++j) {
    int col = j * 16 + l16;
    float bias = b2[col];
#pragma unroll
    for (int reg = 0; reg < 4; ++reg) {
      int grow = r0 + wid * 16 + lq * 4 + reg;
      if (grow < Mpts) {
        float v = acc2[j][reg] + bias;
        cw[(size_t)grow * NCW + col] = f2bf(v);
        s[j] += v; ss[j] += v * v;
      }
    }
  }
#pragma unroll
  for (int j = 0; j < 15; ++j) {
    for (int off = 32; off > 0; off >>= 1) {
      s[j]  += __shfl_xor(s[j],  off);
      ss[j] += __shfl_xor(ss[j], off);
    }
  }
  if (lane == 0) {
#pragma unroll
    for (int j = 0; j < 15; ++j) { red[0][j][wid] = s[j]; red[1][j][wid] = ss[j]; }
  }
  __syncthreads();
  if (t < 15) {
    float S = red[0][t][0] + red[0][t][1] + red[0][t][2] + red[0][t][3];
    atomicAdd(&stats[t], S);
  } else if (t >= 16 && t < 31) {
    int j = t - 16;
    float SS = red[1][j][0] + red[1][j][1] + red[1][j][2] + red[1][j][3];
    atomicAdd(&stats[15 + j], SS);
  }
}

// ================= K2: finalize GroupNorm stats ==============================
__global__ void k2_stats(float* __restrict__ stats)
{
  int j = threadIdx.x;
  if (j < 15) {
    const float inv = 1.0f / (16.0f * (float)Mpts);
    float mu = stats[j] * inv;
    float var = stats[15 + j] * inv - mu * mu;
    stats[30 + j] = mu;
    stats[45 + j] = rsqrtf(var + 1e-5f);
  }
}

// ================= K3: geometry + normalize + gather-sum =====================
__global__ __launch_bounds__(256) void k3_out(
    const float* __restrict__ q_pts, const float* __restrict__ s_pts,
    const ushort* __restrict__ sfb, const int* __restrict__ nb,
    const float* __restrict__ kp, const float* __restrict__ gn_w,
    const float* __restrict__ gn_b, const ushort* __restrict__ cw,
    const float* __restrict__ stats, float* __restrict__ out)
{
  __shared__ float kpt[3][15];
  __shared__ float gnw[240], gnb[240];
  __shared__ float mus[15], rss[15];
  __shared__ float cwl[4][240];
  const int t = threadIdx.x;
  if (t < 45) kpt[t % 3][t / 3] = kp[t];
  if (t >= 64 && t < 79) { mus[t - 64] = stats[30 + (t - 64)]; rss[t - 64] = stats[45 + (t - 64)]; }
  if (t < 240) { gnw[t] = gn_w[t]; gnb[t] = gn_b[t]; }
  __syncthreads();

  const int wid = t >> 6, lane = t & 63;
  const int m = blockIdx.x * 4 + wid;    // grid = M/4 exactly

  int idx = Npts; int ksel = 0; float infl = 0.f;
  if (lane < Hn) {
    idx = nb[m * Hn + lane];
    float qx = q_pts[m * 3 + 0], qy = q_pts[m * 3 + 1], qz = q_pts[m * 3 + 2];
    float px, py, pz;
    if (idx < Npts) { px = s_pts[idx * 3 + 0]; py = s_pts[idx * 3 + 1]; pz = s_pts[idx * 3 + 2]; }
    else            { px = 1.0e6f; py = 1.0e6f; pz = 1.0e6f; }
    float nx = px - qx, ny = py - qy, nz = pz - qz;
    float best = 1e30f;
#pragma unroll
    for (int k = 0; k < Kk; ++k) {
      float dx = nx - kpt[0][k], dy = ny - kpt[1][k], dz = nz - kpt[2][k];
      float d = dx * dx + dy * dy + dz * dz;
      if (d < best) { best = d; ksel = k; }
    }
    infl = 1.f - sqrtf(best);
    infl = infl > 0.f ? infl : 0.f;
  }

  // normalized per-point weights -> LDS (240 values)
  {
    const ushort* cwm = cw + (size_t)m * NCW;
    for (int j = lane; j < NCW; j += 64) {
      float v = bf2f(cwm[j]);
      int g = j >> 4;
      cwl[wid][j] = (v - mus[g]) * rss[g] * gnw[j] + gnb[j];
    }
  }
  __syncthreads();

  // accumulate over 32 neighbors; lane owns channels {2*lane, 2*lane+1}
  float ax = 0.f, ay = 0.f;
  const int widx = lane >> 2;               // cpg index for channel 2*lane
  const ushort* fbase = sfb + 2 * lane;
#pragma unroll 4
  for (int h = 0; h < Hn; ++h) {
    int   ih = __shfl(idx,  h);
    float wI = __shfl(infl, h);
    int   kh = __shfl(ksel, h);
    if (ih < Npts) {
      uint u = *(const uint*)(fbase + (size_t)ih * Cc);
      float fx = __uint_as_float(u << 16);
      float fy = __uint_as_float(u & 0xffff0000u);
      float w = cwl[wid][kh * 16 + widx] * wI;
      ax = fmaf(fx, w, ax);
      ay = fmaf(fy, w, ay);
    }
  }
  float2 o; o.x = ax; o.y = ay;
  *(float2*)(out + (size_t)m * Cc + 2 * lane) = o;
}

// ================= launcher ==================================================
extern "C" void kernel_launch(void* const* d_in, const int* in_sizes, int n_in,
                              void* d_out, int out_size, void* d_ws, size_t ws_size,
                              hipStream_t stream) {
  const float* q_pts  = (const float*)d_in[0];
  const float* s_pts  = (const float*)d_in[1];
  const float* sfeat  = (const float*)d_in[2];
  const int*   nb     = (const int*)d_in[3];
  const float* kp     = (const float*)d_in[4];
  const float* W1     = (const float*)d_in[5];
  const float* b1     = (const float*)d_in[6];
  const float* W2     = (const float*)d_in[7];
  const float* b2     = (const float*)d_in[8];
  const float* gn_w   = (const float*)d_in[9];
  const float* gn_b   = (const float*)d_in[10];
  float* out   = (float*)d_out;

  // ws layout (bytes):
  //   [0,256)            stats (64 f32)
  //   [256, +12.8M)      sfb   bf16 50000x128
  //   next 32768         W1t   bf16 128x128   [n][k]
  //   next 61440         W2t   bf16 240x128   [n][k]
  //   next 24.0M         cw    bf16 50000x240
  char* wsb = (char*)d_ws;
  float*  stats = (float*)wsb;
  ushort* sfb   = (ushort*)(wsb + 256);
  ushort* W1t   = (ushort*)(wsb + 256 + 12800000);
  ushort* W2t   = (ushort*)(wsb + 256 + 12800000 + 32768);
  ushort* cwb   = (ushort*)(wsb + 256 + 12800000 + 32768 + 61440);

  hipMemsetAsync(d_ws, 0, 64 * sizeof(float), stream);

  k0_convert<<<3127, 256, 0, stream>>>(sfeat, W1, W2, sfb, W1t, W2t);
  const int blocks1 = (Mpts + 63) / 64;     // 782
  k1_mlp<<<blocks1, 256, 0, stream>>>(sfb, W1t, b1, W2t, b2, cwb, stats);
  k2_stats<<<1, 64, 0, stream>>>(stats);
  k3_out<<<Mpts / 4, 256, 0, stream>>>(q_pts, s_pts, sfb, nb, kp, gn_w, gn_b, cwb, stats, out);
}

// Round 3
// 165.259 us; speedup vs baseline: 2.3090x; 1.3547x over previous
//
#include <hip/hip_runtime.h>
#include <hip/hip_bf16.h>

#define Mpts 50000
#define Npts 50000
#define Hn 32
#define Cc 128
#define Kk 15
#define NCW 240   // K*CPG = 15*16

typedef __attribute__((ext_vector_type(8))) short short8;
typedef __attribute__((ext_vector_type(4))) float f32x4;

__device__ inline ushort f2bf(float f) {
  __hip_bfloat16 h = __float2bfloat16(f);
  return *reinterpret_cast<ushort*>(&h);
}
__device__ inline float bf2f(ushort u) {
  return __uint_as_float(((uint)u) << 16);
}

// ================= K0w: transpose W1,W2 -> bf16 [n][k]; zero pad row =========
// grid: 24 blocks x 256. b<8: W1 (16384 elems). b in [8,23): W2 (30720 elems).
// b==23: zero sfb row Npts.
__global__ __launch_bounds__(256) void k0_weights(
    const float* __restrict__ W1, const float* __restrict__ W2,
    ushort* __restrict__ W1t, ushort* __restrict__ W2t,
    ushort* __restrict__ sfb)
{
  const int t = threadIdx.x;
  const int b = blockIdx.x;
  if (b < 8) {
    int i0 = b * 2048 + t * 8;               // 8 consecutive elems, same row
    float4 f0 = *(const float4*)(W1 + i0);
    float4 f1 = *(const float4*)(W1 + i0 + 4);
    int k = i0 >> 7, n0 = i0 & 127;
    W1t[(n0 + 0) * Cc + k] = f2bf(f0.x);
    W1t[(n0 + 1) * Cc + k] = f2bf(f0.y);
    W1t[(n0 + 2) * Cc + k] = f2bf(f0.z);
    W1t[(n0 + 3) * Cc + k] = f2bf(f0.w);
    W1t[(n0 + 4) * Cc + k] = f2bf(f1.x);
    W1t[(n0 + 5) * Cc + k] = f2bf(f1.y);
    W1t[(n0 + 6) * Cc + k] = f2bf(f1.z);
    W1t[(n0 + 7) * Cc + k] = f2bf(f1.w);
  } else if (b < 23) {
    int i0 = (b - 8) * 2048 + t * 8;         // 240 % 8 == 0 -> same row
    float4 f0 = *(const float4*)(W2 + i0);
    float4 f1 = *(const float4*)(W2 + i0 + 4);
    int k = i0 / 240, n0 = i0 % 240;
    W2t[(n0 + 0) * Cc + k] = f2bf(f0.x);
    W2t[(n0 + 1) * Cc + k] = f2bf(f0.y);
    W2t[(n0 + 2) * Cc + k] = f2bf(f0.z);
    W2t[(n0 + 3) * Cc + k] = f2bf(f0.w);
    W2t[(n0 + 4) * Cc + k] = f2bf(f1.x);
    W2t[(n0 + 5) * Cc + k] = f2bf(f1.y);
    W2t[(n0 + 6) * Cc + k] = f2bf(f1.z);
    W2t[(n0 + 7) * Cc + k] = f2bf(f1.w);
  } else {
    if (t < 16) {
      short8 z = short8{0,0,0,0,0,0,0,0};
      *(short8*)(sfb + (size_t)Npts * Cc + t * 8) = z;
    }
  }
}

// ================= K1: fused MLP via bf16 MFMA ===============================
// reads fp32 s_feats; writes bf16 copy (for K3), cw bf16, replicated stats.
__global__ __launch_bounds__(256) void k1_mlp(
    const float* __restrict__ sfeat, const ushort* __restrict__ W1t,
    const float* __restrict__ b1, const ushort* __restrict__ W2t,
    const float* __restrict__ b2, ushort* __restrict__ sfb,
    ushort* __restrict__ cw, float* __restrict__ stats)
{
  __shared__ __align__(16) ushort aT[64 * 128];   // swizzled A tile (bf16)
  __shared__ __align__(16) ushort hT[64 * 128];   // swizzled h tile (bf16)
  __shared__ float red[2][15][4];

  const int t = threadIdx.x;
  const int r0 = blockIdx.x * 64;
  const int wid = t >> 6, lane = t & 63;
  const int l16 = lane & 15, lq = lane >> 4;

  // ---- stage A tile: load fp32, convert, write LDS (swizzled) + global sfb --
#pragma unroll
  for (int p = 0; p < 4; ++p) {
    int id = p * 256 + t;          // 16B-chunk index: row = id/16, chunk = id%16
    int r = id >> 4, c = id & 15;
    int g = r0 + r;
    short8 v = short8{0,0,0,0,0,0,0,0};
    if (g < Mpts) {
      const float* src = sfeat + (size_t)g * Cc + c * 8;
      float4 f0 = *(const float4*)(src);
      float4 f1 = *(const float4*)(src + 4);
      union { short8 s; ushort u[8]; } pk;
      pk.u[0] = f2bf(f0.x); pk.u[1] = f2bf(f0.y); pk.u[2] = f2bf(f0.z); pk.u[3] = f2bf(f0.w);
      pk.u[4] = f2bf(f1.x); pk.u[5] = f2bf(f1.y); pk.u[6] = f2bf(f1.z); pk.u[7] = f2bf(f1.w);
      v = pk.s;
      *(short8*)(sfb + (size_t)g * Cc + c * 8) = v;
    }
    int byte = ((r * 256) + c * 16) ^ ((r & 7) << 4);
    *(short8*)((char*)aT + byte) = v;
  }
  __syncthreads();

  // ---- stage 1: h[16 rows per wave][128] ----
  f32x4 acc1[8];
#pragma unroll
  for (int nt = 0; nt < 8; ++nt) acc1[nt] = f32x4{0.f, 0.f, 0.f, 0.f};
  const int arow = wid * 16 + l16;
#pragma unroll
  for (int kt = 0; kt < 4; ++kt) {
    int abyte = ((arow * 256) + (kt * 32 + lq * 8) * 2) ^ ((arow & 7) << 4);
    short8 a = *(const short8*)((const char*)aT + abyte);
#pragma unroll
    for (int nt = 0; nt < 8; ++nt) {
      short8 bfr = *(const short8*)(W1t + (nt * 16 + l16) * Cc + kt * 32 + lq * 8);
      acc1[nt] = __builtin_amdgcn_mfma_f32_16x16x32_bf16(a, bfr, acc1[nt], 0, 0, 0);
    }
  }
  // bias + LeakyReLU -> hT (swizzled, wave-private rows: no barrier needed)
#pragma unroll
  for (int nt = 0; nt < 8; ++nt) {
    int col = nt * 16 + l16;
    float bias = b1[col];
#pragma unroll
    for (int reg = 0; reg < 4; ++reg) {
      float h = acc1[nt][reg] + bias;
      h = h >= 0.f ? h : 0.1f * h;
      int row = wid * 16 + lq * 4 + reg;
      int byte = ((row * 256) + col * 2) ^ ((row & 7) << 4);
      *(ushort*)((char*)hT + byte) = f2bf(h);
    }
  }

  // ---- stage 2: cw[16 rows per wave][240] ----
  f32x4 acc2[15];
#pragma unroll
  for (int j = 0; j < 15; ++j) acc2[j] = f32x4{0.f, 0.f, 0.f, 0.f};
#pragma unroll
  for (int kt = 0; kt < 4; ++kt) {
    int abyte = ((arow * 256) + (kt * 32 + lq * 8) * 2) ^ ((arow & 7) << 4);
    short8 a = *(const short8*)((const char*)hT + abyte);
#pragma unroll
    for (int j = 0; j < 15; ++j) {
      short8 bfr = *(const short8*)(W2t + (j * 16 + l16) * Cc + kt * 32 + lq * 8);
      acc2[j] = __builtin_amdgcn_mfma_f32_16x16x32_bf16(a, bfr, acc2[j], 0, 0, 0);
    }
  }

  float s[15], ss[15];
#pragma unroll
  for (int j = 0; j < 15; ++j) { s[j] = 0.f; ss[j] = 0.f; }
#pragma unroll
  for (int j = 0; j < 15; ++j) {
    int col = j * 16 + l16;
    float bias = b2[col];
#pragma unroll
    for (int reg = 0; reg < 4; ++reg) {
      int grow = r0 + wid * 16 + lq * 4 + reg;
      if (grow < Mpts) {
        float v = acc2[j][reg] + bias;
        cw[(size_t)grow * NCW + col] = f2bf(v);
        s[j] += v; ss[j] += v * v;
      }
    }
  }
#pragma unroll
  for (int j = 0; j < 15; ++j) {
    for (int off = 32; off > 0; off >>= 1) {
      s[j]  += __shfl_xor(s[j],  off);
      ss[j] += __shfl_xor(ss[j], off);
    }
  }
  if (lane == 0) {
#pragma unroll
    for (int j = 0; j < 15; ++j) { red[0][j][wid] = s[j]; red[1][j][wid] = ss[j]; }
  }
  __syncthreads();
  // replicated atomics: 8 accumulator sets, block -> set (blockIdx & 7)
  float* st = stats + (blockIdx.x & 7) * 64;
  if (t < 15) {
    float S = red[0][t][0] + red[0][t][1] + red[0][t][2] + red[0][t][3];
    atomicAdd(&st[t], S);
  } else if (t >= 32 && t < 47) {
    int j = t - 32;
    float SS = red[1][j][0] + red[1][j][1] + red[1][j][2] + red[1][j][3];
    atomicAdd(&st[32 + j], SS);
  }
}

// ================= K2: sum replicas, finalize GroupNorm stats ================
__global__ void k2_stats(float* __restrict__ stats)
{
  int j = threadIdx.x;
  if (j < 15) {
    float S = 0.f, SS = 0.f;
#pragma unroll
    for (int r = 0; r < 8; ++r) { S += stats[r * 64 + j]; SS += stats[r * 64 + 32 + j]; }
    const float inv = 1.0f / (16.0f * (float)Mpts);
    float mu = S * inv;
    float var = SS * inv - mu * mu;
    stats[512 + j] = mu;
    stats[512 + 16 + j] = rsqrtf(var + 1e-5f);
  }
}

// ================= K3: geometry + normalize + gather-sum =====================
__global__ __launch_bounds__(256) void k3_out(
    const float* __restrict__ q_pts, const float* __restrict__ s_pts,
    const ushort* __restrict__ sfb, const int* __restrict__ nb,
    const float* __restrict__ kp, const float* __restrict__ gn_w,
    const float* __restrict__ gn_b, const ushort* __restrict__ cw,
    const float* __restrict__ stats, float* __restrict__ out)
{
  __shared__ float kpt[3][15];
  __shared__ float gnw[240], gnb[240];
  __shared__ float mus[15], rss[15];
  __shared__ float cwl[4][240];
  const int t = threadIdx.x;
  if (t < 45) kpt[t % 3][t / 3] = kp[t];
  if (t >= 64 && t < 79) { mus[t - 64] = stats[512 + (t - 64)]; rss[t - 64] = stats[528 + (t - 64)]; }
  if (t < 240) { gnw[t] = gn_w[t]; gnb[t] = gn_b[t]; }
  __syncthreads();

  const int wid = t >> 6, lane = t & 63;
  const int m = blockIdx.x * 4 + wid;    // grid = M/4 exactly

  int idx = Npts; int ksel = 0; float infl = 0.f;
  if (lane < Hn) {
    idx = nb[m * Hn + lane];
    if (idx > Npts) idx = Npts;
    float qx = q_pts[m * 3 + 0], qy = q_pts[m * 3 + 1], qz = q_pts[m * 3 + 2];
    float px, py, pz;
    if (idx < Npts) { px = s_pts[idx * 3 + 0]; py = s_pts[idx * 3 + 1]; pz = s_pts[idx * 3 + 2]; }
    else            { px = 1.0e6f; py = 1.0e6f; pz = 1.0e6f; }
    float nx = px - qx, ny = py - qy, nz = pz - qz;
    float best = 1e30f;
#pragma unroll
    for (int k = 0; k < Kk; ++k) {
      float dx = nx - kpt[0][k], dy = ny - kpt[1][k], dz = nz - kpt[2][k];
      float d = dx * dx + dy * dy + dz * dz;
      if (d < best) { best = d; ksel = k; }
    }
    infl = 1.f - sqrtf(best);
    infl = infl > 0.f ? infl : 0.f;
  }

  // issue ALL 32 gathers up-front (pad row Npts is zeroed; infl=0 there)
  const ushort* fbase = sfb + 2 * lane;
  uint fv[32];
#pragma unroll
  for (int h = 0; h < Hn; ++h) {
    int ih = __shfl(idx, h);
    fv[h] = *(const uint*)(fbase + (size_t)ih * Cc);
  }

  // normalized per-point weights -> LDS (wave-private row, no barrier)
  {
    const ushort* cwm = cw + (size_t)m * NCW;
    for (int j = lane; j < NCW; j += 64) {
      float v = bf2f(cwm[j]);
      int g = j >> 4;
      cwl[wid][j] = (v - mus[g]) * rss[g] * gnw[j] + gnb[j];
    }
  }

  // accumulate over 32 neighbors; lane owns channels {2*lane, 2*lane+1}
  float ax = 0.f, ay = 0.f;
  const int widx = lane >> 2;
#pragma unroll
  for (int h = 0; h < Hn; ++h) {
    int   kh = __shfl(ksel, h);
    float wI = __shfl(infl, h);
    float w = cwl[wid][kh * 16 + widx] * wI;
    ax = fmaf(__uint_as_float(fv[h] << 16), w, ax);
    ay = fmaf(__uint_as_float(fv[h] & 0xffff0000u), w, ay);
  }
  float2 o; o.x = ax; o.y = ay;
  *(float2*)(out + (size_t)m * Cc + 2 * lane) = o;
}

// ================= launcher ==================================================
extern "C" void kernel_launch(void* const* d_in, const int* in_sizes, int n_in,
                              void* d_out, int out_size, void* d_ws, size_t ws_size,
                              hipStream_t stream) {
  const float* q_pts  = (const float*)d_in[0];
  const float* s_pts  = (const float*)d_in[1];
  const float* sfeat  = (const float*)d_in[2];
  const int*   nb     = (const int*)d_in[3];
  const float* kp     = (const float*)d_in[4];
  const float* W1     = (const float*)d_in[5];
  const float* b1     = (const float*)d_in[6];
  const float* W2     = (const float*)d_in[7];
  const float* b2     = (const float*)d_in[8];
  const float* gn_w   = (const float*)d_in[9];
  const float* gn_b   = (const float*)d_in[10];
  float* out   = (float*)d_out;

  // ws layout (bytes):
  //   [0, 4096)            stats: 8 replicas x 64 f32, results at f32[512..]
  //   [4096, +12,800,256)  sfb   bf16 (50000+1)x128   (row 50000 = zeros)
  //   next 32768           W1t   bf16 128x128  [n][k]
  //   next 61440           W2t   bf16 240x128  [n][k]
  //   next 24,000,000      cw    bf16 50000x240
  char* wsb = (char*)d_ws;
  float*  stats = (float*)wsb;
  ushort* sfb   = (ushort*)(wsb + 4096);
  ushort* W1t   = (ushort*)(wsb + 4096 + 12800256);
  ushort* W2t   = (ushort*)(wsb + 4096 + 12800256 + 32768);
  ushort* cwb   = (ushort*)(wsb + 4096 + 12800256 + 32768 + 61440);

  hipMemsetAsync(d_ws, 0, 4096, stream);

  k0_weights<<<24, 256, 0, stream>>>(W1, W2, W1t, W2t, sfb);
  k1_mlp<<<(Mpts + 63) / 64, 256, 0, stream>>>(sfeat, W1t, b1, W2t, b2, sfb, cwb, stats);
  k2_stats<<<1, 64, 0, stream>>>(stats);
  k3_out<<<Mpts / 4, 256, 0, stream>>>(q_pts, s_pts, sfb, nb, kp, gn_w, gn_b, cwb, stats, out);
}

// Round 4
// 122.123 us; speedup vs baseline: 3.1245x; 1.3532x over previous
//
#include <hip/hip_runtime.h>
#include <hip/hip_bf16.h>

#define Mpts 50000
#define Npts 50000
#define Hn 32
#define Cc 128
#define Kk 15
#define NCW 240   // K*CPG = 15*16

typedef __attribute__((ext_vector_type(8))) short short8;
typedef __attribute__((ext_vector_type(4))) float f32x4;

__device__ inline ushort f2bf(float f) {
  __hip_bfloat16 h = __float2bfloat16(f);
  return *reinterpret_cast<ushort*>(&h);
}
__device__ inline float bf2f(ushort u) {
  return __uint_as_float(((uint)u) << 16);
}

// ================= K0: LDS-transpose W1,W2 -> bf16 [n][k]; zero pad row ======
// grid = 5 blocks x 256: b0,b1 = W1 k-halves; b2,b3 = W2 k-halves; b4 = pad row
__global__ __launch_bounds__(256) void k0_weights(
    const float* __restrict__ W1, const float* __restrict__ W2,
    ushort* __restrict__ W1t, ushort* __restrict__ W2t,
    ushort* __restrict__ sfb)
{
  __shared__ ushort TT[240][66];
  const int t = threadIdx.x;
  const int b = blockIdx.x;
  if (b < 2) {                       // W1: 64 k-rows x 128 n-cols
    const int k0 = b * 64;
#pragma unroll
    for (int i = 0; i < 32; ++i) {
      int e = t + i * 256;           // coalesced
      int r = e >> 7, c = e & 127;
      TT[c][r] = f2bf(W1[(size_t)(k0 + r) * Cc + c]);
    }
    __syncthreads();
    int n = t >> 1, half = t & 1;
    union { short8 v[4]; ushort u[32]; } pk;
#pragma unroll
    for (int i = 0; i < 32; ++i) pk.u[i] = TT[n][half * 32 + i];
#pragma unroll
    for (int q = 0; q < 4; ++q)
      *(short8*)(W1t + (size_t)n * Cc + k0 + half * 32 + q * 8) = pk.v[q];
  } else if (b < 4) {                // W2: 64 k-rows x 240 n-cols
    const int k0 = (b - 2) * 64;
    for (int i = 0; i < 60; ++i) {
      int e = t + i * 256;           // coalesced
      int r = e / 240, c = e % 240;
      TT[c][r] = f2bf(W2[(size_t)(k0 + r) * NCW + c]);
    }
    __syncthreads();
    if (t < 240) {
      union { short8 v[8]; ushort u[64]; } pk;
#pragma unroll
      for (int i = 0; i < 64; ++i) pk.u[i] = TT[t][i];
#pragma unroll
      for (int q = 0; q < 8; ++q)
        *(short8*)(W2t + (size_t)t * Cc + k0 + q * 8) = pk.v[q];
    }
  } else {
    if (t < 16) {
      short8 z = short8{0,0,0,0,0,0,0,0};
      *(short8*)(sfb + (size_t)Npts * Cc + t * 8) = z;
    }
  }
}

// ================= K1: fused MLP via bf16 MFMA (BM=128, 1 LDS buffer) ========
__global__ __launch_bounds__(256, 2) void k1_mlp(
    const float* __restrict__ sfeat, const ushort* __restrict__ W1t,
    const float* __restrict__ b1, const ushort* __restrict__ W2t,
    const float* __restrict__ b2, ushort* __restrict__ sfb,
    ushort* __restrict__ cw, float* __restrict__ stats)
{
  __shared__ __align__(16) ushort shT[128 * 128];   // A tile, later h tile
  __shared__ float red[2][15][4];

  const int t = threadIdx.x;
  const int r0 = blockIdx.x * 128;
  const int wid = t >> 6, lane = t & 63;
  const int l16 = lane & 15, lq = lane >> 4;

  // ---- stage A: fp32 -> bf16 -> LDS (swizzled) + global sfb ----
#pragma unroll
  for (int p = 0; p < 8; ++p) {
    int id = p * 256 + t;            // chunk id: row = id/16, 16B chunk = id%16
    int r = id >> 4, c = id & 15;
    int g = r0 + r;
    short8 v = short8{0,0,0,0,0,0,0,0};
    if (g < Mpts) {
      const float* src = sfeat + (size_t)g * Cc + c * 8;
      float4 f0 = *(const float4*)(src);
      float4 f1 = *(const float4*)(src + 4);
      union { short8 s; ushort u[8]; } pk;
      pk.u[0] = f2bf(f0.x); pk.u[1] = f2bf(f0.y); pk.u[2] = f2bf(f0.z); pk.u[3] = f2bf(f0.w);
      pk.u[4] = f2bf(f1.x); pk.u[5] = f2bf(f1.y); pk.u[6] = f2bf(f1.z); pk.u[7] = f2bf(f1.w);
      v = pk.s;
      *(short8*)(sfb + (size_t)g * Cc + c * 8) = v;
    }
    int byte = ((r * 256) + c * 16) ^ ((r & 7) << 4);
    *(short8*)((char*)shT + byte) = v;
  }
  __syncthreads();
  // NOTE: from here each wave touches ONLY its own 32 rows of shT.

  const int arow = wid * 32 + l16;   // + rt*16
  const int axor = (arow & 7) << 4;  // same for both row-tiles (16%8==0)

  // ---- stage 1: h[32 rows][128] ----
  f32x4 acc1[2][8];
#pragma unroll
  for (int rt = 0; rt < 2; ++rt)
#pragma unroll
    for (int nt = 0; nt < 8; ++nt) acc1[rt][nt] = f32x4{0.f, 0.f, 0.f, 0.f};
#pragma unroll
  for (int kt = 0; kt < 4; ++kt) {
    int off = (kt * 32 + lq * 8) * 2;
    short8 a0 = *(const short8*)((const char*)shT + (((arow)      * 256 + off) ^ axor));
    short8 a1 = *(const short8*)((const char*)shT + (((arow + 16) * 256 + off) ^ axor));
#pragma unroll
    for (int nt = 0; nt < 8; ++nt) {
      short8 b = *(const short8*)(W1t + (size_t)(nt * 16 + l16) * Cc + kt * 32 + lq * 8);
      acc1[0][nt] = __builtin_amdgcn_mfma_f32_16x16x32_bf16(a0, b, acc1[0][nt], 0, 0, 0);
      acc1[1][nt] = __builtin_amdgcn_mfma_f32_16x16x32_bf16(a1, b, acc1[1][nt], 0, 0, 0);
    }
  }
  // bias + LeakyReLU -> shT (own rows; no barrier needed)
#pragma unroll
  for (int nt = 0; nt < 8; ++nt) {
    int col = nt * 16 + l16;
    float bias = b1[col];
#pragma unroll
    for (int rt = 0; rt < 2; ++rt)
#pragma unroll
      for (int reg = 0; reg < 4; ++reg) {
        float h = acc1[rt][nt][reg] + bias;
        h = h >= 0.f ? h : 0.1f * h;
        int row = wid * 32 + rt * 16 + lq * 4 + reg;
        int byte = ((row * 256) + col * 2) ^ ((row & 7) << 4);
        *(ushort*)((char*)shT + byte) = f2bf(h);
      }
  }

  // ---- stage 2: cw[32 rows][240], two col-passes (8 + 7) ----
  float s[15], ss[15];
#pragma unroll
  for (int j = 0; j < 15; ++j) { s[j] = 0.f; ss[j] = 0.f; }
#pragma unroll
  for (int pass = 0; pass < 2; ++pass) {
    const int J0 = pass * 8, NJ = pass ? 7 : 8;
    f32x4 acc2[2][8];
#pragma unroll
    for (int rt = 0; rt < 2; ++rt)
#pragma unroll
      for (int j = 0; j < 8; ++j) acc2[rt][j] = f32x4{0.f, 0.f, 0.f, 0.f};
#pragma unroll
    for (int kt = 0; kt < 4; ++kt) {
      int off = (kt * 32 + lq * 8) * 2;
      short8 a0 = *(const short8*)((const char*)shT + (((arow)      * 256 + off) ^ axor));
      short8 a1 = *(const short8*)((const char*)shT + (((arow + 16) * 256 + off) ^ axor));
#pragma unroll
      for (int j = 0; j < NJ; ++j) {
        short8 b = *(const short8*)(W2t + (size_t)((J0 + j) * 16 + l16) * Cc + kt * 32 + lq * 8);
        acc2[0][j] = __builtin_amdgcn_mfma_f32_16x16x32_bf16(a0, b, acc2[0][j], 0, 0, 0);
        acc2[1][j] = __builtin_amdgcn_mfma_f32_16x16x32_bf16(a1, b, acc2[1][j], 0, 0, 0);
      }
    }
#pragma unroll
    for (int j = 0; j < NJ; ++j) {
      int col = (J0 + j) * 16 + l16;
      float bias = b2[col];
#pragma unroll
      for (int rt = 0; rt < 2; ++rt)
#pragma unroll
        for (int reg = 0; reg < 4; ++reg) {
          int grow = r0 + wid * 32 + rt * 16 + lq * 4 + reg;
          if (grow < Mpts) {
            float v = acc2[rt][j][reg] + bias;
            cw[(size_t)grow * NCW + col] = f2bf(v);
            s[J0 + j] += v; ss[J0 + j] += v * v;
          }
        }
    }
  }

#pragma unroll
  for (int j = 0; j < 15; ++j) {
    for (int off = 32; off > 0; off >>= 1) {
      s[j]  += __shfl_xor(s[j],  off);
      ss[j] += __shfl_xor(ss[j], off);
    }
  }
  if (lane == 0) {
#pragma unroll
    for (int j = 0; j < 15; ++j) { red[0][j][wid] = s[j]; red[1][j][wid] = ss[j]; }
  }
  __syncthreads();
  float* st = stats + (blockIdx.x & 7) * 64;
  if (t < 15) {
    float S = red[0][t][0] + red[0][t][1] + red[0][t][2] + red[0][t][3];
    atomicAdd(&st[t], S);
  } else if (t >= 32 && t < 47) {
    int j = t - 32;
    float SS = red[1][j][0] + red[1][j][1] + red[1][j][2] + red[1][j][3];
    atomicAdd(&st[32 + j], SS);
  }
}

// ================= K2: sum replicas, finalize GroupNorm stats ================
__global__ void k2_stats(float* __restrict__ stats)
{
  int j = threadIdx.x;
  if (j < 15) {
    float S = 0.f, SS = 0.f;
#pragma unroll
    for (int r = 0; r < 8; ++r) { S += stats[r * 64 + j]; SS += stats[r * 64 + 32 + j]; }
    const float inv = 1.0f / (16.0f * (float)Mpts);
    float mu = S * inv;
    float var = SS * inv - mu * mu;
    stats[512 + j] = mu;
    stats[512 + 16 + j] = rsqrtf(var + 1e-5f);
  }
}

// ================= K3: geometry + wtab + gather-sum ==========================
__global__ __launch_bounds__(256) void k3_out(
    const float* __restrict__ q_pts, const float* __restrict__ s_pts,
    const ushort* __restrict__ sfb, const int* __restrict__ nb,
    const float* __restrict__ kp, const float* __restrict__ gn_w,
    const float* __restrict__ gn_b, const ushort* __restrict__ cw,
    const float* __restrict__ stats, float* __restrict__ out)
{
  __shared__ float kpt[3][15];
  __shared__ float gnw[240], gnb[240];
  __shared__ float mus[16], rss[16];
  __shared__ float Atab[240], Btab[240];
  __shared__ float wtab[4][32][16];
  const int t = threadIdx.x;
  if (t < 45) kpt[t % 3][t / 3] = kp[t];
  if (t < 240) { gnw[t] = gn_w[t]; gnb[t] = gn_b[t]; }
  else { int j = t - 240; if (j < 15) { mus[j] = stats[512 + j]; rss[j] = stats[528 + j]; } }
  __syncthreads();

  const int wid = t >> 6, lane = t & 63;
  const int m = blockIdx.x * 4 + wid;    // grid = M/4 exactly

  int idx = Npts; int ksel = 0; float infl = 0.f;
  if (lane < Hn) {
    idx = nb[m * Hn + lane];
    if (idx > Npts) idx = Npts;
    float qx = q_pts[m * 3 + 0], qy = q_pts[m * 3 + 1], qz = q_pts[m * 3 + 2];
    float px, py, pz;
    if (idx < Npts) { px = s_pts[idx * 3 + 0]; py = s_pts[idx * 3 + 1]; pz = s_pts[idx * 3 + 2]; }
    else            { px = 1.0e6f; py = 1.0e6f; pz = 1.0e6f; }
    float nx = px - qx, ny = py - qy, nz = pz - qz;
    float best = 1e30f;
#pragma unroll
    for (int k = 0; k < Kk; ++k) {
      float dx = nx - kpt[0][k], dy = ny - kpt[1][k], dz = nz - kpt[2][k];
      float d = dx * dx + dy * dy + dz * dz;
      if (d < best) { best = d; ksel = k; }
    }
    infl = 1.f - sqrtf(best);
    infl = infl > 0.f ? infl : 0.f;
  } else if (wid == 0) {
    // fold GroupNorm affine: w_norm = v*Atab + Btab
    for (int j = lane - 32; j < NCW; j += 32) {
      int g = j >> 4;
      float a = rss[g] * gnw[j];
      Atab[j] = a;
      Btab[j] = gnb[j] - mus[g] * a;
    }
  }
  __syncthreads();

  // ---- prefetch: 16 x 8B gathers; lane covers channels ch4*4..+3 of h = (lane>>5)+2j
  const int ch4 = lane & 31;
  uint2 fv[16];
  const uint* fb = (const uint*)sfb + ch4 * 2;
#pragma unroll
  for (int j = 0; j < 16; ++j) {
    int h = (lane >> 5) + 2 * j;
    int ih = __shfl(idx, h);
    fv[j] = *(const uint2*)(fb + (size_t)ih * 64);   // row = 64 uints = 256B
  }

  // ---- build per-point weight table (wave-private -> no barrier) ----
  {
    int h = lane >> 1;
    int kh = __shfl(ksel, h);
    float wI = __shfl(infl, h);
    int c0 = (lane & 1) * 8;
    uint4 cwv = *(const uint4*)(cw + (size_t)m * NCW + kh * 16 + c0);  // 8 bf16
    const uint* cu = (const uint*)&cwv;
#pragma unroll
    for (int i = 0; i < 4; ++i) {
      uint u = cu[i];
      int jj = kh * 16 + c0 + 2 * i;
      float v0 = __uint_as_float(u << 16);
      float v1 = __uint_as_float(u & 0xffff0000u);
      wtab[wid][h][c0 + 2 * i]     = fmaf(v0, Atab[jj],     Btab[jj])     * wI;
      wtab[wid][h][c0 + 2 * i + 1] = fmaf(v1, Atab[jj + 1], Btab[jj + 1]) * wI;
    }
  }

  // ---- main loop: 16 iters, 1 ds_read + 4 unpack + 4 fma each ----
  float a0 = 0.f, a1 = 0.f, a2 = 0.f, a3 = 0.f;
  const int cpg = ch4 >> 1;
#pragma unroll
  for (int j = 0; j < 16; ++j) {
    int h = (lane >> 5) + 2 * j;
    float w = wtab[wid][h][cpg];
    uint ux = fv[j].x, uy = fv[j].y;
    a0 = fmaf(__uint_as_float(ux << 16),         w, a0);
    a1 = fmaf(__uint_as_float(ux & 0xffff0000u), w, a1);
    a2 = fmaf(__uint_as_float(uy << 16),         w, a2);
    a3 = fmaf(__uint_as_float(uy & 0xffff0000u), w, a3);
  }
  a0 += __shfl_xor(a0, 32);
  a1 += __shfl_xor(a1, 32);
  a2 += __shfl_xor(a2, 32);
  a3 += __shfl_xor(a3, 32);
  if (lane < 32) {
    float4 o; o.x = a0; o.y = a1; o.z = a2; o.w = a3;
    *(float4*)(out + (size_t)m * Cc + ch4 * 4) = o;
  }
}

// ================= launcher ==================================================
extern "C" void kernel_launch(void* const* d_in, const int* in_sizes, int n_in,
                              void* d_out, int out_size, void* d_ws, size_t ws_size,
                              hipStream_t stream) {
  const float* q_pts  = (const float*)d_in[0];
  const float* s_pts  = (const float*)d_in[1];
  const float* sfeat  = (const float*)d_in[2];
  const int*   nb     = (const int*)d_in[3];
  const float* kp     = (const float*)d_in[4];
  const float* W1     = (const float*)d_in[5];
  const float* b1     = (const float*)d_in[6];
  const float* W2     = (const float*)d_in[7];
  const float* b2     = (const float*)d_in[8];
  const float* gn_w   = (const float*)d_in[9];
  const float* gn_b   = (const float*)d_in[10];
  float* out   = (float*)d_out;

  // ws layout (bytes):
  //   [0, 4096)            stats: 8 replicas x 64 f32; results at f32[512..]
  //   [4096, +12,800,256)  sfb   bf16 (50000+1)x128   (row 50000 = zeros)
  //   next 32768           W1t   bf16 128x128  [n][k]
  //   next 61440           W2t   bf16 240x128  [n][k]
  //   next 24,000,000      cw    bf16 50000x240
  char* wsb = (char*)d_ws;
  float*  stats = (float*)wsb;
  ushort* sfb   = (ushort*)(wsb + 4096);
  ushort* W1t   = (ushort*)(wsb + 4096 + 12800256);
  ushort* W2t   = (ushort*)(wsb + 4096 + 12800256 + 32768);
  ushort* cwb   = (ushort*)(wsb + 4096 + 12800256 + 32768 + 61440);

  hipMemsetAsync(d_ws, 0, 4096, stream);

  k0_weights<<<5, 256, 0, stream>>>(W1, W2, W1t, W2t, sfb);
  k1_mlp<<<(Mpts + 127) / 128, 256, 0, stream>>>(sfeat, W1t, b1, W2t, b2, sfb, cwb, stats);
  k2_stats<<<1, 64, 0, stream>>>(stats);
  k3_out<<<Mpts / 4, 256, 0, stream>>>(q_pts, s_pts, sfb, nb, kp, gn_w, gn_b, cwb, stats, out);
}

// Round 5
// 114.583 us; speedup vs baseline: 3.3301x; 1.0658x over previous
//
#include <hip/hip_runtime.h>
#include <hip/hip_bf16.h>

#define Mpts 50000
#define Npts 50000
#define Hn 32
#define Cc 128
#define Kk 15
#define NCW 240   // K*CPG = 15*16

typedef __attribute__((ext_vector_type(8))) short short8;
typedef __attribute__((ext_vector_type(4))) float f32x4;
typedef __attribute__((ext_vector_type(2))) float f32x2;

__device__ inline ushort f2bf(float f) {
  __hip_bfloat16 h = __float2bfloat16(f);
  return *reinterpret_cast<ushort*>(&h);
}
__device__ inline float bf2f(ushort u) {
  return __uint_as_float(((uint)u) << 16);
}

// ================= K0: transpose W1,W2 -> bf16 [n][k]; zero pad row & stats ==
// grid = 5 blocks x 256: b0,b1 = W1 k-halves; b2,b3 = W2 k-halves; b4 = init
__global__ __launch_bounds__(256) void k0_weights(
    const float* __restrict__ W1, const float* __restrict__ W2,
    ushort* __restrict__ W1t, ushort* __restrict__ W2t,
    ushort* __restrict__ sfb, float* __restrict__ stats)
{
  __shared__ ushort TT[240][66];
  const int t = threadIdx.x;
  const int b = blockIdx.x;
  if (b < 2) {                       // W1: 64 k-rows x 128 n-cols
    const int k0 = b * 64;
#pragma unroll
    for (int i = 0; i < 32; ++i) {
      int e = t + i * 256;           // coalesced
      int r = e >> 7, c = e & 127;
      TT[c][r] = f2bf(W1[(size_t)(k0 + r) * Cc + c]);
    }
    __syncthreads();
    int n = t >> 1, half = t & 1;
    union { short8 v[4]; ushort u[32]; } pk;
#pragma unroll
    for (int i = 0; i < 32; ++i) pk.u[i] = TT[n][half * 32 + i];
#pragma unroll
    for (int q = 0; q < 4; ++q)
      *(short8*)(W1t + (size_t)n * Cc + k0 + half * 32 + q * 8) = pk.v[q];
  } else if (b < 4) {                // W2: 64 k-rows x 240 n-cols
    const int k0 = (b - 2) * 64;
    for (int i = 0; i < 60; ++i) {
      int e = t + i * 256;           // coalesced
      int r = e / 240, c = e % 240;
      TT[c][r] = f2bf(W2[(size_t)(k0 + r) * NCW + c]);
    }
    __syncthreads();
    if (t < 240) {
      union { short8 v[8]; ushort u[64]; } pk;
#pragma unroll
      for (int i = 0; i < 64; ++i) pk.u[i] = TT[t][i];
#pragma unroll
      for (int q = 0; q < 8; ++q)
        *(short8*)(W2t + (size_t)t * Cc + k0 + q * 8) = pk.v[q];
    }
  } else {
    if (t < 16) {
      short8 z = short8{0,0,0,0,0,0,0,0};
      *(short8*)(sfb + (size_t)Npts * Cc + t * 8) = z;
    }
    if (t < 128) {                   // zero 512 stats floats
      float4 z4 = make_float4(0.f, 0.f, 0.f, 0.f);
      *(float4*)(stats + t * 4) = z4;
    }
  }
}

// ================= K1: fused MLP via bf16 MFMA (BM=128, 1 LDS buffer) ========
__global__ __launch_bounds__(256, 2) void k1_mlp(
    const float* __restrict__ sfeat, const ushort* __restrict__ W1t,
    const float* __restrict__ b1, const ushort* __restrict__ W2t,
    const float* __restrict__ b2, ushort* __restrict__ sfb,
    ushort* __restrict__ cw, float* __restrict__ stats)
{
  __shared__ __align__(16) ushort shT[128 * 128];   // A tile, later h tile
  __shared__ float red[2][15][4];

  const int t = threadIdx.x;
  const int r0 = blockIdx.x * 128;
  const int wid = t >> 6, lane = t & 63;
  const int l16 = lane & 15, lq = lane >> 4;

  // ---- stage A: batch-issue all loads, then cvt + write LDS/global ----
  float4 fA[8], fB[8];
#pragma unroll
  for (int p = 0; p < 8; ++p) {
    int id = p * 256 + t;
    int r = id >> 4, c = id & 15;
    int g = r0 + r;
    fA[p] = make_float4(0.f, 0.f, 0.f, 0.f);
    fB[p] = make_float4(0.f, 0.f, 0.f, 0.f);
    if (g < Mpts) {
      const float* src = sfeat + (size_t)g * Cc + c * 8;
      fA[p] = *(const float4*)(src);
      fB[p] = *(const float4*)(src + 4);
    }
  }
#pragma unroll
  for (int p = 0; p < 8; ++p) {
    int id = p * 256 + t;
    int r = id >> 4, c = id & 15;
    int g = r0 + r;
    union { short8 s; ushort u[8]; } pk;
    pk.u[0] = f2bf(fA[p].x); pk.u[1] = f2bf(fA[p].y); pk.u[2] = f2bf(fA[p].z); pk.u[3] = f2bf(fA[p].w);
    pk.u[4] = f2bf(fB[p].x); pk.u[5] = f2bf(fB[p].y); pk.u[6] = f2bf(fB[p].z); pk.u[7] = f2bf(fB[p].w);
    if (g < Mpts) *(short8*)(sfb + (size_t)g * Cc + c * 8) = pk.s;
    int byte = ((r * 256) + c * 16) ^ ((r & 7) << 4);
    *(short8*)((char*)shT + byte) = pk.s;
  }
  __syncthreads();
  // from here each wave touches ONLY its own 32 rows of shT

  const int arow = wid * 32 + l16;   // + rt*16
  const int axor = (arow & 7) << 4;

  // ---- stage 1: h[32 rows][128] ----
  f32x4 acc1[2][8];
#pragma unroll
  for (int rt = 0; rt < 2; ++rt)
#pragma unroll
    for (int nt = 0; nt < 8; ++nt) acc1[rt][nt] = f32x4{0.f, 0.f, 0.f, 0.f};
#pragma unroll
  for (int kt = 0; kt < 4; ++kt) {
    int off = (kt * 32 + lq * 8) * 2;
    short8 a0 = *(const short8*)((const char*)shT + (((arow)      * 256 + off) ^ axor));
    short8 a1 = *(const short8*)((const char*)shT + (((arow + 16) * 256 + off) ^ axor));
#pragma unroll
    for (int nt = 0; nt < 8; ++nt) {
      short8 b = *(const short8*)(W1t + (size_t)(nt * 16 + l16) * Cc + kt * 32 + lq * 8);
      acc1[0][nt] = __builtin_amdgcn_mfma_f32_16x16x32_bf16(a0, b, acc1[0][nt], 0, 0, 0);
      acc1[1][nt] = __builtin_amdgcn_mfma_f32_16x16x32_bf16(a1, b, acc1[1][nt], 0, 0, 0);
    }
  }
  // bias + LeakyReLU -> shT (own rows; no barrier needed)
#pragma unroll
  for (int nt = 0; nt < 8; ++nt) {
    int col = nt * 16 + l16;
    float bias = b1[col];
#pragma unroll
    for (int rt = 0; rt < 2; ++rt)
#pragma unroll
      for (int reg = 0; reg < 4; ++reg) {
        float h = acc1[rt][nt][reg] + bias;
        h = h >= 0.f ? h : 0.1f * h;
        int row = wid * 32 + rt * 16 + lq * 4 + reg;
        int byte = ((row * 256) + col * 2) ^ ((row & 7) << 4);
        *(ushort*)((char*)shT + byte) = f2bf(h);
      }
  }

  // ---- stage 2: cw[32 rows][240], two col-passes (8 + 7) ----
  float s[15], ss[15];
#pragma unroll
  for (int j = 0; j < 15; ++j) { s[j] = 0.f; ss[j] = 0.f; }
#pragma unroll
  for (int pass = 0; pass < 2; ++pass) {
    const int J0 = pass * 8, NJ = pass ? 7 : 8;
    f32x4 acc2[2][8];
#pragma unroll
    for (int rt = 0; rt < 2; ++rt)
#pragma unroll
      for (int j = 0; j < 8; ++j) acc2[rt][j] = f32x4{0.f, 0.f, 0.f, 0.f};
#pragma unroll
    for (int kt = 0; kt < 4; ++kt) {
      int off = (kt * 32 + lq * 8) * 2;
      short8 a0 = *(const short8*)((const char*)shT + (((arow)      * 256 + off) ^ axor));
      short8 a1 = *(const short8*)((const char*)shT + (((arow + 16) * 256 + off) ^ axor));
#pragma unroll
      for (int j = 0; j < NJ; ++j) {
        short8 b = *(const short8*)(W2t + (size_t)((J0 + j) * 16 + l16) * Cc + kt * 32 + lq * 8);
        acc2[0][j] = __builtin_amdgcn_mfma_f32_16x16x32_bf16(a0, b, acc2[0][j], 0, 0, 0);
        acc2[1][j] = __builtin_amdgcn_mfma_f32_16x16x32_bf16(a1, b, acc2[1][j], 0, 0, 0);
      }
    }
#pragma unroll
    for (int j = 0; j < NJ; ++j) {
      int col = (J0 + j) * 16 + l16;
      float bias = b2[col];
#pragma unroll
      for (int rt = 0; rt < 2; ++rt)
#pragma unroll
        for (int reg = 0; reg < 4; ++reg) {
          int grow = r0 + wid * 32 + rt * 16 + lq * 4 + reg;
          if (grow < Mpts) {
            float v = acc2[rt][j][reg] + bias;
            cw[(size_t)grow * NCW + col] = f2bf(v);
            s[J0 + j] += v; ss[J0 + j] += v * v;
          }
        }
    }
  }

#pragma unroll
  for (int j = 0; j < 15; ++j) {
    for (int off = 32; off > 0; off >>= 1) {
      s[j]  += __shfl_xor(s[j],  off);
      ss[j] += __shfl_xor(ss[j], off);
    }
  }
  if (lane == 0) {
#pragma unroll
    for (int j = 0; j < 15; ++j) { red[0][j][wid] = s[j]; red[1][j][wid] = ss[j]; }
  }
  __syncthreads();
  float* st = stats + (blockIdx.x & 7) * 64;
  if (t < 15) {
    float S = red[0][t][0] + red[0][t][1] + red[0][t][2] + red[0][t][3];
    atomicAdd(&st[t], S);
  } else if (t >= 32 && t < 47) {
    int j = t - 32;
    float SS = red[1][j][0] + red[1][j][1] + red[1][j][2] + red[1][j][3];
    atomicAdd(&st[32 + j], SS);
  }
}

// ================= K3: stats finalize + geometry + wtab + gather-sum =========
__global__ __launch_bounds__(256) void k3_out(
    const float* __restrict__ q_pts, const float* __restrict__ s_pts,
    const ushort* __restrict__ sfb, const int* __restrict__ nb,
    const float* __restrict__ kp, const float* __restrict__ gn_w,
    const float* __restrict__ gn_b, const ushort* __restrict__ cw,
    const float* __restrict__ stats, float* __restrict__ out)
{
  __shared__ float kpt[3][15];
  __shared__ float mus[16], rss[16];
  __shared__ float Atab[240], Btab[240];
  __shared__ float wtab[4][32][17];
  const int t = threadIdx.x;

  // fused k2: finalize GroupNorm stats from 8 replicas (per block, cheap)
  if (t < 15) {
    float S = 0.f, SS = 0.f;
#pragma unroll
    for (int r = 0; r < 8; ++r) { S += stats[r * 64 + t]; SS += stats[r * 64 + 32 + t]; }
    const float inv = 1.0f / (16.0f * (float)Mpts);
    float mu = S * inv;
    float var = SS * inv - mu * mu;
    mus[t] = mu;
    rss[t] = rsqrtf(var + 1e-5f);
  } else if (t < 60) {
    kpt[(t - 15) % 3][(t - 15) / 3] = kp[t - 15];
  }
  __syncthreads();
  if (t < 240) {       // fold GroupNorm affine: w_norm = v*Atab + Btab
    int g = t >> 4;
    float a = rss[g] * gn_w[t];
    Atab[t] = a;
    Btab[t] = gn_b[t] - mus[g] * a;
  }
  __syncthreads();

  const int wid = t >> 6, lane = t & 63;
  const int m = blockIdx.x * 4 + wid;    // grid = M/4 exactly

  int idx = Npts; int ksel = 0; float infl = 0.f;
  if (lane < Hn) {
    idx = nb[m * Hn + lane];
    if (idx > Npts) idx = Npts;
    float qx = q_pts[m * 3 + 0], qy = q_pts[m * 3 + 1], qz = q_pts[m * 3 + 2];
    float px, py, pz;
    if (idx < Npts) { px = s_pts[idx * 3 + 0]; py = s_pts[idx * 3 + 1]; pz = s_pts[idx * 3 + 2]; }
    else            { px = 1.0e6f; py = 1.0e6f; pz = 1.0e6f; }
    float nx = px - qx, ny = py - qy, nz = pz - qz;
    float best = 1e30f;
#pragma unroll
    for (int k = 0; k < Kk; ++k) {
      float dx = nx - kpt[0][k], dy = ny - kpt[1][k], dz = nz - kpt[2][k];
      float d = dx * dx + dy * dy + dz * dz;
      if (d < best) { best = d; ksel = k; }
    }
    infl = 1.f - sqrtf(best);
    infl = infl > 0.f ? infl : 0.f;
  }

  // ---- prefetch: 8 x 16B gathers; lane owns channels ch8*8..+7, h=(lane>>4)+4j
  const int ch8 = lane & 15;
  const uint4* fb = (const uint4*)sfb;
  uint4 fv[8];
#pragma unroll
  for (int j = 0; j < 8; ++j) {
    int h = (lane >> 4) + 4 * j;
    int ih = __shfl(idx, h);
    fv[j] = fb[ih * 16 + ch8];      // row = 16 uint4 = 256 B; fits int32
  }

  // ---- per-point weight table (wave-private -> no barrier) ----
  {
    int h = lane >> 1;
    int kh = __shfl(ksel, h);
    float wI = __shfl(infl, h);
    int c0 = (lane & 1) * 8;
    uint4 cwv = *(const uint4*)(cw + (size_t)m * NCW + kh * 16 + c0);  // 8 bf16
    const uint* cu = (const uint*)&cwv;
#pragma unroll
    for (int i = 0; i < 4; ++i) {
      uint u = cu[i];
      int jj = kh * 16 + c0 + 2 * i;
      float v0 = __uint_as_float(u << 16);
      float v1 = __uint_as_float(u & 0xffff0000u);
      wtab[wid][h][c0 + 2 * i]     = fmaf(v0, Atab[jj],     Btab[jj])     * wI;
      wtab[wid][h][c0 + 2 * i + 1] = fmaf(v1, Atab[jj + 1], Btab[jj + 1]) * wI;
    }
  }

  // ---- main loop: 8 iters, 1 ds_read + 8 unpack + 4 pk_fma each ----
  f32x2 acc0 = {0.f, 0.f}, acc1 = {0.f, 0.f}, acc2 = {0.f, 0.f}, acc3 = {0.f, 0.f};
#pragma unroll
  for (int j = 0; j < 8; ++j) {
    int h = (lane >> 4) + 4 * j;
    float w = wtab[wid][h][ch8];
    f32x2 w2 = {w, w};
    uint ux = fv[j].x, uy = fv[j].y, uz = fv[j].z, uw = fv[j].w;
    f32x2 p0 = {__uint_as_float(ux << 16), __uint_as_float(ux & 0xffff0000u)};
    f32x2 p1 = {__uint_as_float(uy << 16), __uint_as_float(uy & 0xffff0000u)};
    f32x2 p2 = {__uint_as_float(uz << 16), __uint_as_float(uz & 0xffff0000u)};
    f32x2 p3 = {__uint_as_float(uw << 16), __uint_as_float(uw & 0xffff0000u)};
    acc0 = __builtin_elementwise_fma(p0, w2, acc0);
    acc1 = __builtin_elementwise_fma(p1, w2, acc1);
    acc2 = __builtin_elementwise_fma(p2, w2, acc2);
    acc3 = __builtin_elementwise_fma(p3, w2, acc3);
  }
  // reduce across the 4 h-quarters (lanes ^16, ^32)
#pragma unroll
  for (int off = 16; off <= 32; off <<= 1) {
    acc0[0] += __shfl_xor(acc0[0], off); acc0[1] += __shfl_xor(acc0[1], off);
    acc1[0] += __shfl_xor(acc1[0], off); acc1[1] += __shfl_xor(acc1[1], off);
    acc2[0] += __shfl_xor(acc2[0], off); acc2[1] += __shfl_xor(acc2[1], off);
    acc3[0] += __shfl_xor(acc3[0], off); acc3[1] += __shfl_xor(acc3[1], off);
  }
  if (lane < 16) {
    float4 o0; o0.x = acc0[0]; o0.y = acc0[1]; o0.z = acc1[0]; o0.w = acc1[1];
    float4 o1; o1.x = acc2[0]; o1.y = acc2[1]; o1.z = acc3[0]; o1.w = acc3[1];
    float* op = out + (size_t)m * Cc + ch8 * 8;
    *(float4*)(op)     = o0;
    *(float4*)(op + 4) = o1;
  }
}

// ================= launcher ==================================================
extern "C" void kernel_launch(void* const* d_in, const int* in_sizes, int n_in,
                              void* d_out, int out_size, void* d_ws, size_t ws_size,
                              hipStream_t stream) {
  const float* q_pts  = (const float*)d_in[0];
  const float* s_pts  = (const float*)d_in[1];
  const float* sfeat  = (const float*)d_in[2];
  const int*   nb     = (const int*)d_in[3];
  const float* kp     = (const float*)d_in[4];
  const float* W1     = (const float*)d_in[5];
  const float* b1     = (const float*)d_in[6];
  const float* W2     = (const float*)d_in[7];
  const float* b2     = (const float*)d_in[8];
  const float* gn_w   = (const float*)d_in[9];
  const float* gn_b   = (const float*)d_in[10];
  float* out   = (float*)d_out;

  // ws layout (bytes):
  //   [0, 4096)            stats: 8 replicas x 64 f32
  //   [4096, +12,800,256)  sfb   bf16 (50000+1)x128   (row 50000 = zeros)
  //   next 32768           W1t   bf16 128x128  [n][k]
  //   next 61440           W2t   bf16 240x128  [n][k]
  //   next 24,000,000      cw    bf16 50000x240
  char* wsb = (char*)d_ws;
  float*  stats = (float*)wsb;
  ushort* sfb   = (ushort*)(wsb + 4096);
  ushort* W1t   = (ushort*)(wsb + 4096 + 12800256);
  ushort* W2t   = (ushort*)(wsb + 4096 + 12800256 + 32768);
  ushort* cwb   = (ushort*)(wsb + 4096 + 12800256 + 32768 + 61440);

  k0_weights<<<5, 256, 0, stream>>>(W1, W2, W1t, W2t, sfb, stats);
  k1_mlp<<<(Mpts + 127) / 128, 256, 0, stream>>>(sfeat, W1t, b1, W2t, b2, sfb, cwb, stats);
  k3_out<<<Mpts / 4, 256, 0, stream>>>(q_pts, s_pts, sfb, nb, kp, gn_w, gn_b, cwb, stats, out);
}